// Round 1
// baseline (21524.915 us; speedup 1.0000x reference)
//
#include <hip/hip_runtime.h>
#include <math.h>

// DistillerGRU: T=512, B=64, H=1024, 2 layers.
// Strategy R1: fp16 MFMA for all matmuls, f32 gates/state, phased execution:
//   [cvt] -> per chunk of 64 t: [gemm gx (parallel over t)] -> [64 sequential step kernels]
// Layer-0 y0 (fp16) overwrites x16 in place and feeds layer-1 gx GEMMs.

#define TT 512
#define BB 64
#define HH 1024
#define GG 3072            // 3*H
#define CH 64              // timesteps per gx chunk
#define NCHUNK (TT / CH)

typedef _Float16 half8 __attribute__((ext_vector_type(8)));
typedef _Float16 f16x4 __attribute__((ext_vector_type(4)));
typedef float f32x4 __attribute__((ext_vector_type(4)));

// ---------------- f32 -> f16 conversion ----------------
__global__ void cvt_f32_f16_kernel(const float* __restrict__ src,
                                   _Float16* __restrict__ dst, long n) {
  long i = ((long)blockIdx.x * blockDim.x + threadIdx.x) * 4;
  long stride = (long)gridDim.x * blockDim.x * 4;
  for (long e = i; e < n; e += stride) {
    float4 v = *(const float4*)(src + e);
    f16x4 h;
    h.x = (_Float16)v.x; h.y = (_Float16)v.y;
    h.z = (_Float16)v.z; h.w = (_Float16)v.w;
    *(f16x4*)(dst + e) = h;
  }
}

// ---------------- h init (per layer) ----------------
__global__ void init_h_kernel(const float* __restrict__ src,
                              float* __restrict__ h32,
                              _Float16* __restrict__ h16) {
  int i = blockIdx.x * 256 + threadIdx.x;  // grid = B*H/256
  float v = src[i];
  h32[i] = v;
  h16[i] = (_Float16)v;
}

// ---------------- final hidden-state copy ----------------
__global__ void copy_hfinal_kernel(const float* __restrict__ h0f,
                                   const float* __restrict__ h1f,
                                   float* __restrict__ dst) {
  int i = blockIdx.x * 256 + threadIdx.x;  // grid = 2*B*H/256
  const int n = BB * HH;
  dst[i] = (i < n) ? h0f[i] : h1f[i - n];
}

__global__ void sentinel_kernel(float* out) { out[0] = 12345.0f; }  // ws-too-small marker

// ---------------- input-side GEMM: C[4096,3072] = A[4096,1024] @ W[3072,1024]^T + bias ----
// 128x128 tile, BK=64, double-buffered LDS, reg-staged (T14 split), fp16 MFMA 16x16x32.
__global__ __launch_bounds__(256) void gemm_gx_kernel(
    const _Float16* __restrict__ A,   // [CH*BB, HH] fp16
    const _Float16* __restrict__ W,   // [GG, HH] fp16
    const float* __restrict__ bias,   // [GG]
    float* __restrict__ C)            // [CH*BB, GG] f32
{
  __shared__ _Float16 As[2][128 * 64];
  __shared__ _Float16 Ws[2][128 * 64];
  const int tid = threadIdx.x;
  const int wid = tid >> 6, lane = tid & 63;
  const int bm = blockIdx.x / (GG / 128);
  const int bn = blockIdx.x % (GG / 128);
  const int m0 = bm * 128, n0 = bn * 128;
  const int wm = (wid >> 1) * 64, wn = (wid & 1) * 64;  // 2x2 wave split, 64x64 per wave

  f32x4 acc[4][4] = {};
  half8 ra[4], rw[4];
  int rowq[4], colq[4];
#pragma unroll
  for (int j = 0; j < 4; ++j) {       // each thread stages 4x16B for A and W
    int q = tid + 256 * j;            // q in [0,1024): 16B chunk id of a 128x64 fp16 tile
    rowq[j] = q >> 3;
    colq[j] = (q & 7) * 8;
  }

  // prologue: stage K-tile 0
#pragma unroll
  for (int j = 0; j < 4; ++j) {
    ra[j] = *(const half8*)&A[(long)(m0 + rowq[j]) * HH + colq[j]];
    rw[j] = *(const half8*)&W[(long)(n0 + rowq[j]) * HH + colq[j]];
  }
#pragma unroll
  for (int j = 0; j < 4; ++j) {
    *(half8*)&As[0][rowq[j] * 64 + colq[j]] = ra[j];
    *(half8*)&Ws[0][rowq[j] * 64 + colq[j]] = rw[j];
  }
  __syncthreads();

  for (int kt = 0; kt < 16; ++kt) {   // K = 16 * 64
    const int buf = kt & 1;
    if (kt < 15) {                    // issue next-tile global loads early
      const int k0 = (kt + 1) * 64;
#pragma unroll
      for (int j = 0; j < 4; ++j) {
        ra[j] = *(const half8*)&A[(long)(m0 + rowq[j]) * HH + k0 + colq[j]];
        rw[j] = *(const half8*)&W[(long)(n0 + rowq[j]) * HH + k0 + colq[j]];
      }
    }
#pragma unroll
    for (int ks = 0; ks < 2; ++ks) {  // two K=32 MFMA sub-steps per staged tile
      half8 af[4], bf[4];
      const int kof = ks * 32 + (lane >> 4) * 8;
#pragma unroll
      for (int mt = 0; mt < 4; ++mt)
        af[mt] = *(const half8*)&As[buf][(wm + mt * 16 + (lane & 15)) * 64 + kof];
#pragma unroll
      for (int nt = 0; nt < 4; ++nt)
        bf[nt] = *(const half8*)&Ws[buf][(wn + nt * 16 + (lane & 15)) * 64 + kof];
#pragma unroll
      for (int mt = 0; mt < 4; ++mt)
#pragma unroll
        for (int nt = 0; nt < 4; ++nt)
          acc[mt][nt] = __builtin_amdgcn_mfma_f32_16x16x32_f16(af[mt], bf[nt], acc[mt][nt], 0, 0, 0);
    }
    if (kt < 15) {                    // write next tile to the other LDS buffer (late write)
#pragma unroll
      for (int j = 0; j < 4; ++j) {
        *(half8*)&As[buf ^ 1][rowq[j] * 64 + colq[j]] = ra[j];
        *(half8*)&Ws[buf ^ 1][rowq[j] * 64 + colq[j]] = rw[j];
      }
    }
    __syncthreads();
  }

  // epilogue: D[row=(lane>>4)*4+j][col=lane&15] per 16x16 tile; add bias, store f32
#pragma unroll
  for (int nt = 0; nt < 4; ++nt) {
    const int gcol = n0 + wn + nt * 16 + (lane & 15);
    const float bv = bias[gcol];
#pragma unroll
    for (int mt = 0; mt < 4; ++mt) {
#pragma unroll
      for (int j = 0; j < 4; ++j) {
        const int grow = m0 + wm + mt * 16 + (lane >> 4) * 4 + j;
        C[(long)grow * GG + gcol] = acc[mt][nt][j] + bv;
      }
    }
  }
}

// ---------------- fused GRU step ----------------
// 64 WGs x 256 threads. WG owns h-indices [16*blk, 16*blk+16) => gate cols {hs, H+hs, 2H+hs}+[0,16).
// Wave i computes batch rows [16i,16i+16) x all 3 gate tiles -> full gate set in-wave, no exchange.
// h/Wh fragments loaded directly from global (L2-resident working set ~1 MB/XCD).
__global__ __launch_bounds__(256) void gru_step_kernel(
    const _Float16* __restrict__ hin,   // [B,H] fp16 (prev step)
    const _Float16* __restrict__ Wh,    // [G,H] fp16
    const float* __restrict__ bh,       // [G]
    const float* __restrict__ gx,       // [B,G] f32, this t (includes bx)
    float* __restrict__ h32,            // [B,H] f32 state (in/out, lane-private slice)
    _Float16* __restrict__ hout,        // [B,H] fp16 (next step's hin; layer0: y0 slot in x16)
    float* __restrict__ y32)            // layer1: d_out + t*B*H, else nullptr
{
  const int tid = threadIdx.x;
  const int wid = tid >> 6, lane = tid & 63;
  const int hs = blockIdx.x * 16;
  const int mrow = wid * 16;
  const int lcol = lane & 15;
  const int lk = (lane >> 4) * 8;

  f32x4 acc0 = {}, acc1 = {}, acc2 = {};
  const _Float16* ap  = hin + (mrow + lcol) * HH + lk;
  const _Float16* bp0 = Wh + (long)(hs + lcol) * HH + lk;           // r rows
  const _Float16* bp1 = bp0 + (long)HH * HH;                        // z rows
  const _Float16* bp2 = bp1 + (long)HH * HH;                        // n rows
#pragma unroll 4
  for (int kb = 0; kb < HH; kb += 32) {
    half8 a = *(const half8*)(ap + kb);
    acc0 = __builtin_amdgcn_mfma_f32_16x16x32_f16(a, *(const half8*)(bp0 + kb), acc0, 0, 0, 0);
    acc1 = __builtin_amdgcn_mfma_f32_16x16x32_f16(a, *(const half8*)(bp1 + kb), acc1, 0, 0, 0);
    acc2 = __builtin_amdgcn_mfma_f32_16x16x32_f16(a, *(const half8*)(bp2 + kb), acc2, 0, 0, 0);
  }

  const int hcol = hs + lcol;
  const float rb = bh[hcol], zb = bh[HH + hcol], nb = bh[2 * HH + hcol];
#pragma unroll
  for (int j = 0; j < 4; ++j) {
    const int b = mrow + (lane >> 4) * 4 + j;
    const float rh = acc0[j] + rb;
    const float zh = acc1[j] + zb;
    const float nh = acc2[j] + nb;
    const float rx = gx[b * GG + hcol];
    const float zx = gx[b * GG + HH + hcol];
    const float nx = gx[b * GG + 2 * HH + hcol];
    const float r = 1.f / (1.f + expf(-(rx + rh)));
    const float z = 1.f / (1.f + expf(-(zx + zh)));
    const float n = tanhf(nx + r * nh);
    const int hi = b * HH + hcol;
    const float hn = (1.f - z) * n + z * h32[hi];
    h32[hi] = hn;
    hout[hi] = (_Float16)hn;
    if (y32) y32[hi] = hn;
  }
}

// ---------------- launch ----------------
extern "C" void kernel_launch(void* const* d_in, const int* in_sizes, int n_in,
                              void* d_out, int out_size, void* d_ws, size_t ws_size,
                              hipStream_t stream) {
  const float* x   = (const float*)d_in[0];
  const float* h0  = (const float*)d_in[1];
  const float* Wx0 = (const float*)d_in[2];
  const float* bx0 = (const float*)d_in[3];
  const float* Wh0 = (const float*)d_in[4];
  const float* bh0 = (const float*)d_in[5];
  const float* Wx1 = (const float*)d_in[6];
  const float* bx1 = (const float*)d_in[7];
  const float* Wh1 = (const float*)d_in[8];
  const float* bh1 = (const float*)d_in[9];
  float* out = (float*)d_out;

  const long nTBH = (long)TT * BB * HH;  // 33,554,432
  const long nGH  = (long)GG * HH;       // 3,145,728
  const long nBH  = (long)BB * HH;       // 65,536

  char* p = (char*)d_ws;
  _Float16* x16    = (_Float16*)p;  p += nTBH * 2;        // x fp16, later overwritten by y0 fp16
  _Float16* wx0_16 = (_Float16*)p;  p += nGH * 2;
  _Float16* wh0_16 = (_Float16*)p;  p += nGH * 2;
  _Float16* wx1_16 = (_Float16*)p;  p += nGH * 2;
  _Float16* wh1_16 = (_Float16*)p;  p += nGH * 2;
  float*    gx_buf = (float*)p;     p += (long)CH * BB * GG * 4;  // 50.3 MB chunk buffer
  float*    h32_0  = (float*)p;     p += nBH * 4;
  float*    h32_1  = (float*)p;     p += nBH * 4;
  _Float16* h16a   = (_Float16*)p;  p += nBH * 2;
  _Float16* h16b   = (_Float16*)p;  p += nBH * 2;
  if ((size_t)(p - (char*)d_ws) > ws_size) {   // ~143.4 MB needed
    sentinel_kernel<<<1, 1, 0, stream>>>(out); // absmax ~12345 => ws too small
    return;
  }

  // conversions
  cvt_f32_f16_kernel<<<2048, 256, 0, stream>>>(x, x16, nTBH);
  cvt_f32_f16_kernel<<<512, 256, 0, stream>>>(Wx0, wx0_16, nGH);
  cvt_f32_f16_kernel<<<512, 256, 0, stream>>>(Wh0, wh0_16, nGH);
  cvt_f32_f16_kernel<<<512, 256, 0, stream>>>(Wx1, wx1_16, nGH);
  cvt_f32_f16_kernel<<<512, 256, 0, stream>>>(Wh1, wh1_16, nGH);

  const int gemm_grid = (CH * BB / 128) * (GG / 128);  // 32*24 = 768

  // ---- layer 0 ----
  init_h_kernel<<<nBH / 256, 256, 0, stream>>>(h0, h32_0, h16a);
  for (int c = 0; c < NCHUNK; ++c) {
    gemm_gx_kernel<<<gemm_grid, 256, 0, stream>>>(x16 + (long)c * CH * BB * HH, wx0_16, bx0, gx_buf);
    for (int tt = 0; tt < CH; ++tt) {
      const int t = c * CH + tt;
      const _Float16* hin = (t == 0) ? h16a : (x16 + (long)(t - 1) * BB * HH);
      _Float16* hout = x16 + (long)t * BB * HH;  // y0 fp16 over consumed x16 rows
      gru_step_kernel<<<64, 256, 0, stream>>>(hin, wh0_16, bh0,
                                              gx_buf + (long)tt * BB * GG,
                                              h32_0, hout, nullptr);
    }
  }

  // ---- layer 1 ----
  init_h_kernel<<<nBH / 256, 256, 0, stream>>>(h0 + nBH, h32_1, h16a);
  for (int c = 0; c < NCHUNK; ++c) {
    gemm_gx_kernel<<<gemm_grid, 256, 0, stream>>>(x16 + (long)c * CH * BB * HH, wx1_16, bx1, gx_buf);
    for (int tt = 0; tt < CH; ++tt) {
      const int t = c * CH + tt;
      const _Float16* hin = (t & 1) ? h16b : h16a;
      _Float16* hout     = (t & 1) ? h16a : h16b;
      gru_step_kernel<<<64, 256, 0, stream>>>(hin, wh1_16, bh1,
                                              gx_buf + (long)tt * BB * GG,
                                              h32_1, hout, out + (long)t * BB * HH);
    }
  }

  copy_hfinal_kernel<<<512, 256, 0, stream>>>(h32_0, h32_1, out + nTBH);
}

// Round 2
// 15938.318 us; speedup vs baseline: 1.3505x; 1.3505x over previous
//
#include <hip/hip_runtime.h>
#include <math.h>

// DistillerGRU: T=512, B=64, H=1024, 2 layers.
// R2: single persistent cooperative kernel; 513 grid-barrier phases run both
// layers pipelined (L0 step t and L1 step t-1 concurrently). Per layer-step:
// gates = [h_prev | xin] @ [Wh | Wx]^T + biases, K=2048 fp16 MFMA, f32 gates,
// f32 h-master in registers, fp16 h exchanged via global + agent fences.

#define TT 512
#define BB 64
#define HH 1024
#define GG 3072
#define NWG 128            // 64 WGs per layer

typedef _Float16 half8 __attribute__((ext_vector_type(8)));
typedef _Float16 f16x4 __attribute__((ext_vector_type(4)));
typedef float f32x4 __attribute__((ext_vector_type(4)));

// ---------------- f32 -> f16 conversion (row-major copy) ----------------
__global__ void cvt_f32_f16_kernel(const float* __restrict__ src,
                                   _Float16* __restrict__ dst, long n) {
  long i = ((long)blockIdx.x * blockDim.x + threadIdx.x) * 4;
  long stride = (long)gridDim.x * blockDim.x * 4;
  for (long e = i; e < n; e += stride) {
    float4 v = *(const float4*)(src + e);
    f16x4 h;
    h.x = (_Float16)v.x; h.y = (_Float16)v.y;
    h.z = (_Float16)v.z; h.w = (_Float16)v.w;
    *(f16x4*)(dst + e) = h;
  }
}

// ---------------- weight pack: [Wh | Wx] -> fragment-contiguous ----------------
// wp[tile(192)][kst(64)][lane(64)][8], element = W[tile*16+(lane&15)][k],
// k = kst*32 + (lane>>4)*8 + sub; kst<32 from Wh, else Wx. Tiles: r=0..63,
// z=64..127, n=128..191 (g = tile*16 + (lane&15) globally).
__global__ void cvt_wpack_kernel(const float* __restrict__ Wh,
                                 const float* __restrict__ Wx,
                                 _Float16* __restrict__ wp) {
  int gid = blockIdx.x * 256 + threadIdx.x;   // 192*64*64 = 786432 threads
  int lane = gid & 63;
  int kst = (gid >> 6) & 63;
  int tile = gid >> 12;
  int g = tile * 16 + (lane & 15);
  int ko = (lane >> 4) * 8;
  const float* src = (kst < 32) ? (Wh + (long)g * HH + kst * 32 + ko)
                                : (Wx + (long)g * HH + (kst - 32) * 32 + ko);
  half8 h;
#pragma unroll
  for (int j = 0; j < 8; ++j) h[j] = (_Float16)src[j];
  *(half8*)(wp + (((long)tile * 64 + kst) * 64 + lane) * 8) = h;
}

// ---------------- h init: h0 f32 -> h0f slot0 (L0), h1f slot1 (L1) ----------------
__global__ void init_hf_kernel(const float* __restrict__ h0,
                               _Float16* __restrict__ h0f,
                               _Float16* __restrict__ h1f) {
  int i = blockIdx.x * 256 + threadIdx.x;  // grid = 2*B*H/256 = 512
  const int n = BB * HH;
  float v = h0[i];
  if (i < n) h0f[i] = (_Float16)v;               // slot 0
  else       h1f[n + (i - n)] = (_Float16)v;     // slot 1
}

__global__ void sentinel_kernel(float* out) { out[0] = 12345.0f; }

// ---------------- persistent 2-layer GRU ----------------
__global__ __launch_bounds__(256) void gru_persist(
    const _Float16* __restrict__ x16,   // [T,B,H] fp16 row-major
    const _Float16* __restrict__ w0p,   // packed layer0 [Wh0|Wx0]
    const _Float16* __restrict__ w1p,   // packed layer1
    const float* __restrict__ bx0, const float* __restrict__ bh0,
    const float* __restrict__ bx1, const float* __restrict__ bh1,
    const float* __restrict__ h0in,     // [2,B,H] f32
    _Float16* __restrict__ h0f,         // [2][B*H] fp16 double buffer
    _Float16* __restrict__ h1f,
    float* __restrict__ out,            // [T*B*H + 2*B*H]
    unsigned* __restrict__ bar)
{
  const int tid = threadIdx.x;
  const int wid = tid >> 6, lane = tid & 63;
  const int layer = blockIdx.x >> 6;
  const int c = blockIdx.x & 63;        // 16-col group
  const int hs = c * 16;
  const int lcol = lane & 15;
  const int lk = (lane >> 4) * 8;

  const _Float16* wf = layer ? w1p : w0p;
  const float* bx = layer ? bx1 : bx0;
  const float* bh = layer ? bh1 : bh0;
  _Float16* hbuf = layer ? h1f : h0f;

  const int col = hs + lcol;
  const float rb  = bh[col] + bx[col];
  const float zb  = bh[HH + col] + bx[HH + col];
  const float nhb = bh[2 * HH + col];
  const float nxb = bx[2 * HH + col];

  const int r0 = wid * 16 + (lane >> 4) * 4;   // first of 4 batch rows
  float hreg[4];
#pragma unroll
  for (int j = 0; j < 4; ++j)
    hreg[j] = h0in[layer * BB * HH + (r0 + j) * HH + col];

  const _Float16* wr = wf + ((long)c * 64) * 512;          // tile c
  const _Float16* wz = wf + ((long)(64 + c) * 64) * 512;   // tile 64+c
  const _Float16* wn = wf + ((long)(128 + c) * 64) * 512;  // tile 128+c

  unsigned tgt = NWG;
  for (int p = 0; p <= 512; ++p) {
    const bool act = layer ? (p >= 1) : (p < 512);
    if (act) {
      const int t = p - layer;
      const int rd = p & 1;
      const _Float16* hsrc = hbuf + rd * (BB * HH);
      const _Float16* xsrc = layer ? (h0f + rd * (BB * HH))
                                   : (x16 + (long)t * (BB * HH));
      const _Float16* ah = hsrc + (wid * 16 + lcol) * HH + lk;
      const _Float16* ax = xsrc + (wid * 16 + lcol) * HH + lk;

      f32x4 aR = {}, aZ = {}, aNH = {}, aNX = {};
#pragma unroll 8
      for (int ks = 0; ks < 32; ++ks) {   // h-half (K 0..1023)
        half8 a  = *(const half8*)(ah + ks * 32);
        half8 b0 = *(const half8*)(wr + ks * 512 + lane * 8);
        half8 b1 = *(const half8*)(wz + ks * 512 + lane * 8);
        half8 b2 = *(const half8*)(wn + ks * 512 + lane * 8);
        aR  = __builtin_amdgcn_mfma_f32_16x16x32_f16(a, b0, aR, 0, 0, 0);
        aZ  = __builtin_amdgcn_mfma_f32_16x16x32_f16(a, b1, aZ, 0, 0, 0);
        aNH = __builtin_amdgcn_mfma_f32_16x16x32_f16(a, b2, aNH, 0, 0, 0);
      }
#pragma unroll 8
      for (int ks = 0; ks < 32; ++ks) {   // x-half (K 1024..2047)
        half8 a  = *(const half8*)(ax + ks * 32);
        half8 b0 = *(const half8*)(wr + (32 + ks) * 512 + lane * 8);
        half8 b1 = *(const half8*)(wz + (32 + ks) * 512 + lane * 8);
        half8 b2 = *(const half8*)(wn + (32 + ks) * 512 + lane * 8);
        aR  = __builtin_amdgcn_mfma_f32_16x16x32_f16(a, b0, aR, 0, 0, 0);
        aZ  = __builtin_amdgcn_mfma_f32_16x16x32_f16(a, b1, aZ, 0, 0, 0);
        aNX = __builtin_amdgcn_mfma_f32_16x16x32_f16(a, b2, aNX, 0, 0, 0);
      }

      _Float16* hdst = hbuf + (rd ^ 1) * (BB * HH);
      float* yo = out + (long)t * (BB * HH);
#pragma unroll
      for (int j = 0; j < 4; ++j) {
        const int row = r0 + j;
        const float r = 1.f / (1.f + expf(-(aR[j] + rb)));
        const float z = 1.f / (1.f + expf(-(aZ[j] + zb)));
        const float n = tanhf(aNX[j] + nxb + r * (aNH[j] + nhb));
        const float hn = (1.f - z) * n + z * hreg[j];
        hreg[j] = hn;
        hdst[row * HH + col] = (_Float16)hn;
        if (layer) yo[row * HH + col] = hn;
      }
    }
    // ---- device-wide barrier (monotone counter, agent fences) ----
    __syncthreads();
    if (tid == 0) {
      __builtin_amdgcn_fence(__ATOMIC_RELEASE, "agent");  // L2 writeback
      __hip_atomic_fetch_add(bar, 1u, __ATOMIC_RELAXED, __HIP_MEMORY_SCOPE_AGENT);
      while (__hip_atomic_load(bar, __ATOMIC_RELAXED, __HIP_MEMORY_SCOPE_AGENT) < tgt)
        __builtin_amdgcn_s_sleep(2);
      __builtin_amdgcn_fence(__ATOMIC_ACQUIRE, "agent");  // L1+L2 invalidate
    }
    __syncthreads();
    tgt += NWG;
  }

  // final hidden states: out[T*B*H + layer*B*H + ...] = f32 h-master
#pragma unroll
  for (int j = 0; j < 4; ++j)
    out[(long)TT * BB * HH + layer * BB * HH + (r0 + j) * HH + col] = hreg[j];
}

// ---------------- launch ----------------
extern "C" void kernel_launch(void* const* d_in, const int* in_sizes, int n_in,
                              void* d_out, int out_size, void* d_ws, size_t ws_size,
                              hipStream_t stream) {
  const float* x   = (const float*)d_in[0];
  const float* h0  = (const float*)d_in[1];
  const float* Wx0 = (const float*)d_in[2];
  const float* bx0 = (const float*)d_in[3];
  const float* Wh0 = (const float*)d_in[4];
  const float* bh0 = (const float*)d_in[5];
  const float* Wx1 = (const float*)d_in[6];
  const float* bx1 = (const float*)d_in[7];
  const float* Wh1 = (const float*)d_in[8];
  const float* bh1 = (const float*)d_in[9];
  float* out = (float*)d_out;

  const long nTBH = (long)TT * BB * HH;     // 33,554,432
  const long nWP  = (long)192 * 64 * 64 * 8;  // 6,291,456 halves per layer
  const long nBH  = (long)BB * HH;

  char* p = (char*)d_ws;
  _Float16* x16 = (_Float16*)p;  p += nTBH * 2;     // 67.1 MB
  _Float16* w0p = (_Float16*)p;  p += nWP * 2;      // 12.6 MB
  _Float16* w1p = (_Float16*)p;  p += nWP * 2;      // 12.6 MB
  _Float16* h0f = (_Float16*)p;  p += 2 * nBH * 2;  // 256 KB
  _Float16* h1f = (_Float16*)p;  p += 2 * nBH * 2;  // 256 KB
  unsigned* bar = (unsigned*)p;  p += 256;
  if ((size_t)(p - (char*)d_ws) > ws_size) {
    sentinel_kernel<<<1, 1, 0, stream>>>(out);
    return;
  }

  hipMemsetAsync(bar, 0, sizeof(unsigned), stream);
  cvt_f32_f16_kernel<<<2048, 256, 0, stream>>>(x, x16, nTBH);
  cvt_wpack_kernel<<<3072, 256, 0, stream>>>(Wh0, Wx0, w0p);
  cvt_wpack_kernel<<<3072, 256, 0, stream>>>(Wh1, Wx1, w1p);
  init_hf_kernel<<<512, 256, 0, stream>>>(h0, h0f, h1f);

  void* args[] = {(void*)&x16, (void*)&w0p, (void*)&w1p,
                  (void*)&bx0, (void*)&bh0, (void*)&bx1, (void*)&bh1,
                  (void*)&h0, (void*)&h0f, (void*)&h1f,
                  (void*)&out, (void*)&bar};
  hipError_t e = hipLaunchCooperativeKernel((const void*)gru_persist,
                                            dim3(NWG), dim3(256), args, 0, stream);
  if (e != hipSuccess) {
    // fallback: plain launch (128 WGs on 256 CUs are co-resident)
    gru_persist<<<NWG, 256, 0, stream>>>(x16, w0p, w1p, bx0, bh0, bx1, bh1,
                                         h0, h0f, h1f, out, bar);
  }
}

// Round 3
// 6646.281 us; speedup vs baseline: 3.2386x; 2.3981x over previous
//
#include <hip/hip_runtime.h>
#include <math.h>

// DistillerGRU: T=512, B=64, H=1024, 2 layers.
// R3: persistent cooperative kernel, 513 phases, layers pipelined.
//  - Weights resident in VGPRs (48 half8/wave), loaded once. Zero steady-state
//    weight traffic.
//  - No cache fences: h exchanged with relaxed agent-scope (sc0/sc1) atomics,
//    coherent at L3; L2 contents (x16 etc.) never invalidated.
//  - 256 WGs: layer x 64 col-groups x 2 batch-halves. 4 waves/WG split K=2048
//    into quarters (waves 0,1 = h-half, 2,3 = x-half -> nh/nx split natural),
//    partials reduced via LDS, waves 0,1 do gate math + h update.

#define TT 512
#define BB 64
#define HH 1024
#define NWG 256
#define NBH (BB * HH)

typedef _Float16 half8 __attribute__((ext_vector_type(8)));
typedef _Float16 f16x4 __attribute__((ext_vector_type(4)));
typedef float f32x4 __attribute__((ext_vector_type(4)));
typedef unsigned long long u64_t;

// ---------------- f32 -> f16 conversion ----------------
__global__ void cvt_f32_f16_kernel(const float* __restrict__ src,
                                   _Float16* __restrict__ dst, long n) {
  long i = ((long)blockIdx.x * blockDim.x + threadIdx.x) * 4;
  long stride = (long)gridDim.x * blockDim.x * 4;
  for (long e = i; e < n; e += stride) {
    float4 v = *(const float4*)(src + e);
    f16x4 h;
    h.x = (_Float16)v.x; h.y = (_Float16)v.y;
    h.z = (_Float16)v.z; h.w = (_Float16)v.w;
    *(f16x4*)(dst + e) = h;
  }
}

// ---------------- weight pack: [Wh | Wx] -> fragment-contiguous ----------------
// wp[tile(192)][kst(64)][lane(64)][8]; element = W[tile*16+(lane&15)][k],
// k = kst*32 + (lane>>4)*8 + sub; kst<32 from Wh, kst>=32 from Wx.
__global__ void cvt_wpack_kernel(const float* __restrict__ Wh,
                                 const float* __restrict__ Wx,
                                 _Float16* __restrict__ wp) {
  int gid = blockIdx.x * 256 + threadIdx.x;   // 192*64*64 threads
  int lane = gid & 63;
  int kst = (gid >> 6) & 63;
  int tile = gid >> 12;
  int g = tile * 16 + (lane & 15);
  int ko = (lane >> 4) * 8;
  const float* src = (kst < 32) ? (Wh + (long)g * HH + kst * 32 + ko)
                                : (Wx + (long)g * HH + (kst - 32) * 32 + ko);
  half8 h;
#pragma unroll
  for (int j = 0; j < 8; ++j) h[j] = (_Float16)src[j];
  *(half8*)(wp + (((long)tile * 64 + kst) * 64 + lane) * 8) = h;
}

// ---------------- h init ----------------
__global__ void init_hf_kernel(const float* __restrict__ h0,
                               _Float16* __restrict__ h0f,
                               _Float16* __restrict__ h1f) {
  int i = blockIdx.x * 256 + threadIdx.x;  // grid = 2*B*H/256
  const int n = NBH;
  float v = h0[i];
  if (i < n) h0f[i] = (_Float16)v;               // layer0 slot 0
  else       h1f[n + (i - n)] = (_Float16)v;     // layer1 slot 1
}

__global__ void sentinel_kernel(float* out) { out[0] = 12345.0f; }

// ---------------- persistent 2-layer GRU ----------------
__global__ __launch_bounds__(256, 1) void gru_persist(
    const _Float16* __restrict__ x16,
    const _Float16* __restrict__ w0p, const _Float16* __restrict__ w1p,
    const float* __restrict__ bx0, const float* __restrict__ bh0,
    const float* __restrict__ bx1, const float* __restrict__ bh1,
    const float* __restrict__ h0in,
    _Float16* __restrict__ h0f, _Float16* __restrict__ h1f,
    float* __restrict__ out, unsigned* __restrict__ bar)
{
  const int tid = threadIdx.x;
  const int wid = tid >> 6, lane = tid & 63;
  const int layer = blockIdx.x >> 7;
  const int rb_ = blockIdx.x & 127;
  const int c = rb_ >> 1;           // col-group 0..63
  const int brow = (rb_ & 1) * 32;  // batch half
  const int lcol = lane & 15;
  const int lk = (lane >> 4) * 8;

  const _Float16* wf = layer ? w1p : w0p;
  const float* bx = layer ? bx1 : bx0;
  const float* bhp = layer ? bh1 : bh0;
  _Float16* hbuf = layer ? h1f : h0f;

  const int col = c * 16 + lcol;
  const float rbv = bhp[col] + bx[col];
  const float zbv = bhp[HH + col] + bx[HH + col];
  const float nhb = bhp[2 * HH + col];
  const float nxb = bx[2 * HH + col];

  // ---- weights resident in VGPRs: wave wid covers kst = wid*16 .. wid*16+15 ----
  half8 wb[3][16];
#pragma unroll
  for (int g = 0; g < 3; ++g) {
    const long tile = (long)(g * 64 + c);
#pragma unroll
    for (int i = 0; i < 16; ++i)
      wb[g][i] = *(const half8*)(wf + (tile * 64 + (wid * 16 + i)) * 512 + lane * 8);
  }

  // f32 h master state (waves 0,1): rows er0..er0+3 at column col
  const int er0 = brow + wid * 16 + (lane >> 4) * 4;
  float hreg[4] = {0.f, 0.f, 0.f, 0.f};
  if (wid < 2) {
#pragma unroll
    for (int j = 0; j < 4; ++j)
      hreg[j] = h0in[layer * NBH + (er0 + j) * HH + col];
  }

  __shared__ f32x4 red[4][2][3][64];

  const int kb = (wid & 1) * 512;   // K-base within this wave's source
  unsigned tgt = NWG;
  for (int p = 0; p <= TT; ++p) {
    const bool act = layer ? (p >= 1) : (p < TT);
    if (act) {
      const int t = p - layer;
      const int rd = p & 1;
      const _Float16* hsrc = hbuf + rd * NBH;
      const _Float16* xsrc = layer ? (h0f + rd * NBH) : (x16 + (long)t * NBH);
      const _Float16* asrc = (wid < 2) ? hsrc : xsrc;
      const u64_t* abase = (const u64_t*)(asrc + (long)(brow + lcol) * HH + kb + lk);
      // strides in u64 units: row=256, m-tile=16*256=4096, ks=8

      // issue all 64 coherent loads back-to-back (one L3 latency)
      u64_t av[2][16][2];
#pragma unroll
      for (int m = 0; m < 2; ++m)
#pragma unroll
        for (int ks = 0; ks < 16; ++ks) {
          const u64_t* q = abase + m * 4096 + ks * 8;
          av[m][ks][0] = __hip_atomic_load(q,     __ATOMIC_RELAXED, __HIP_MEMORY_SCOPE_AGENT);
          av[m][ks][1] = __hip_atomic_load(q + 1, __ATOMIC_RELAXED, __HIP_MEMORY_SCOPE_AGENT);
        }

      f32x4 acc[2][3] = {};
#pragma unroll
      for (int m = 0; m < 2; ++m)
#pragma unroll
        for (int ks = 0; ks < 16; ++ks) {
          union { u64_t u[2]; half8 h; } cv;
          cv.u[0] = av[m][ks][0]; cv.u[1] = av[m][ks][1];
#pragma unroll
          for (int g = 0; g < 3; ++g)
            acc[m][g] = __builtin_amdgcn_mfma_f32_16x16x32_f16(cv.h, wb[g][ks], acc[m][g], 0, 0, 0);
        }

      // partial reduction across the 4 K-quarter waves
#pragma unroll
      for (int m = 0; m < 2; ++m)
#pragma unroll
        for (int g = 0; g < 3; ++g)
          red[wid][m][g][lane] = acc[m][g];
      __syncthreads();

      if (wid < 2) {
        const int m = wid;
        f32x4 rs = red[0][m][0][lane] + red[1][m][0][lane] + red[2][m][0][lane] + red[3][m][0][lane];
        f32x4 zs = red[0][m][1][lane] + red[1][m][1][lane] + red[2][m][1][lane] + red[3][m][1][lane];
        f32x4 nh = red[0][m][2][lane] + red[1][m][2][lane];
        f32x4 nx = red[2][m][2][lane] + red[3][m][2][lane];
        _Float16* hdst = hbuf + (rd ^ 1) * NBH;
        float* yo = out + (long)t * NBH;
#pragma unroll
        for (int j = 0; j < 4; ++j) {
          const int row = er0 + j;
          const float rg = 1.f / (1.f + __expf(-(rs[j] + rbv)));
          const float zg = 1.f / (1.f + __expf(-(zs[j] + zbv)));
          const float ng = tanhf(nx[j] + nxb + rg * (nh[j] + nhb));
          const float hn = (1.f - zg) * ng + zg * hreg[j];
          hreg[j] = hn;
          if (layer) yo[row * HH + col] = hn;
          // pack 2 adjacent cols into one u32 coherent store (even lanes store)
          _Float16 hf = (_Float16)hn;
          unsigned us = (unsigned)__builtin_bit_cast(unsigned short, hf);
          unsigned other = (unsigned)__shfl_xor((int)us, 1);
          if ((lane & 1) == 0) {
            unsigned packed = us | (other << 16);
            __hip_atomic_store((unsigned*)&hdst[row * HH + col], packed,
                               __ATOMIC_RELAXED, __HIP_MEMORY_SCOPE_AGENT);
          }
        }
      }
    }
    // ---- fence-free global barrier ----
    __syncthreads();   // drains each wave's vmcnt (sc1 stores visible at L3)
    if (tid == 0) {
      asm volatile("s_waitcnt vmcnt(0)" ::: "memory");
      __hip_atomic_fetch_add(bar, 1u, __ATOMIC_RELAXED, __HIP_MEMORY_SCOPE_AGENT);
      while (__hip_atomic_load(bar, __ATOMIC_RELAXED, __HIP_MEMORY_SCOPE_AGENT) < tgt)
        __builtin_amdgcn_s_sleep(1);
    }
    __syncthreads();
    tgt += NWG;
  }

  // final hidden states (f32 master)
  if (wid < 2) {
#pragma unroll
    for (int j = 0; j < 4; ++j)
      out[(long)TT * NBH + layer * NBH + (er0 + j) * HH + col] = hreg[j];
  }
}

// ---------------- launch ----------------
extern "C" void kernel_launch(void* const* d_in, const int* in_sizes, int n_in,
                              void* d_out, int out_size, void* d_ws, size_t ws_size,
                              hipStream_t stream) {
  const float* x   = (const float*)d_in[0];
  const float* h0  = (const float*)d_in[1];
  const float* Wx0 = (const float*)d_in[2];
  const float* bx0 = (const float*)d_in[3];
  const float* Wh0 = (const float*)d_in[4];
  const float* bh0 = (const float*)d_in[5];
  const float* Wx1 = (const float*)d_in[6];
  const float* bx1 = (const float*)d_in[7];
  const float* Wh1 = (const float*)d_in[8];
  const float* bh1 = (const float*)d_in[9];
  float* out = (float*)d_out;

  const long nTBH = (long)TT * BB * HH;
  const long nWP  = (long)192 * 64 * 64 * 8;

  char* p = (char*)d_ws;
  _Float16* x16 = (_Float16*)p;  p += nTBH * 2;     // 67.1 MB
  _Float16* w0p = (_Float16*)p;  p += nWP * 2;      // 12.6 MB
  _Float16* w1p = (_Float16*)p;  p += nWP * 2;      // 12.6 MB
  _Float16* h0f = (_Float16*)p;  p += 2 * (long)NBH * 2;
  _Float16* h1f = (_Float16*)p;  p += 2 * (long)NBH * 2;
  unsigned* bar = (unsigned*)p;  p += 256;
  if ((size_t)(p - (char*)d_ws) > ws_size) {
    sentinel_kernel<<<1, 1, 0, stream>>>(out);
    return;
  }

  hipMemsetAsync(bar, 0, sizeof(unsigned), stream);
  cvt_f32_f16_kernel<<<2048, 256, 0, stream>>>(x, x16, nTBH);
  cvt_wpack_kernel<<<3072, 256, 0, stream>>>(Wh0, Wx0, w0p);
  cvt_wpack_kernel<<<3072, 256, 0, stream>>>(Wh1, Wx1, w1p);
  init_hf_kernel<<<512, 256, 0, stream>>>(h0, h0f, h1f);

  void* args[] = {(void*)&x16, (void*)&w0p, (void*)&w1p,
                  (void*)&bx0, (void*)&bh0, (void*)&bx1, (void*)&bh1,
                  (void*)&h0, (void*)&h0f, (void*)&h1f,
                  (void*)&out, (void*)&bar};
  hipError_t e = hipLaunchCooperativeKernel((const void*)gru_persist,
                                            dim3(NWG), dim3(256), args, 0, stream);
  if (e != hipSuccess) {
    gru_persist<<<NWG, 256, 0, stream>>>(x16, w0p, w1p, bx0, bh0, bx1, bh1,
                                         h0, h0f, h1f, out, bar);
  }
}

// Round 4
// 5428.761 us; speedup vs baseline: 3.9650x; 1.2243x over previous
//
#include <hip/hip_runtime.h>
#include <math.h>

// DistillerGRU: T=512, B=64, H=1024, 2 layers.
// R4: persistent cooperative kernel, 513 phases, layers pipelined (skew 1).
//  - Weights resident in VGPRs (48 half8/wave), loaded once.
//  - h exchanged via relaxed agent-scope (L3-coherent) atomics; x16 read with
//    plain L2-cached loads (read-only input).
//  - Tree barrier: 8 arrive counters (256B-strided lines, 32 RMWs each),
//    master scans + posts epoch on a separate release line; pollers read-only.

#define TT 512
#define BB 64
#define HH 1024
#define NWG 256
#define NBH (BB * HH)

typedef _Float16 half8 __attribute__((ext_vector_type(8)));
typedef _Float16 f16x4 __attribute__((ext_vector_type(4)));
typedef float f32x4 __attribute__((ext_vector_type(4)));
typedef unsigned long long u64_t;

// ---------------- f32 -> f16 conversion ----------------
__global__ void cvt_f32_f16_kernel(const float* __restrict__ src,
                                   _Float16* __restrict__ dst, long n) {
  long i = ((long)blockIdx.x * blockDim.x + threadIdx.x) * 4;
  long stride = (long)gridDim.x * blockDim.x * 4;
  for (long e = i; e < n; e += stride) {
    float4 v = *(const float4*)(src + e);
    f16x4 h;
    h.x = (_Float16)v.x; h.y = (_Float16)v.y;
    h.z = (_Float16)v.z; h.w = (_Float16)v.w;
    *(f16x4*)(dst + e) = h;
  }
}

// ---------------- weight pack: [Wh | Wx] -> fragment-contiguous ----------------
// wp[tile(192)][kst(64)][lane(64)][8]; element = W[tile*16+(lane&15)][k],
// k = kst*32 + (lane>>4)*8 + sub; kst<32 from Wh, kst>=32 from Wx.
__global__ void cvt_wpack_kernel(const float* __restrict__ Wh,
                                 const float* __restrict__ Wx,
                                 _Float16* __restrict__ wp) {
  int gid = blockIdx.x * 256 + threadIdx.x;   // 192*64*64 threads
  int lane = gid & 63;
  int kst = (gid >> 6) & 63;
  int tile = gid >> 12;
  int g = tile * 16 + (lane & 15);
  int ko = (lane >> 4) * 8;
  const float* src = (kst < 32) ? (Wh + (long)g * HH + kst * 32 + ko)
                                : (Wx + (long)g * HH + (kst - 32) * 32 + ko);
  half8 h;
#pragma unroll
  for (int j = 0; j < 8; ++j) h[j] = (_Float16)src[j];
  *(half8*)(wp + (((long)tile * 64 + kst) * 64 + lane) * 8) = h;
}

// ---------------- h init ----------------
__global__ void init_hf_kernel(const float* __restrict__ h0,
                               _Float16* __restrict__ h0f,
                               _Float16* __restrict__ h1f) {
  int i = blockIdx.x * 256 + threadIdx.x;  // grid = 2*B*H/256
  const int n = NBH;
  float v = h0[i];
  if (i < n) h0f[i] = (_Float16)v;               // layer0 slot 0
  else       h1f[n + (i - n)] = (_Float16)v;     // layer1 slot 1
}

__global__ void sentinel_kernel(float* out) { out[0] = 12345.0f; }

// ---------------- persistent 2-layer GRU ----------------
__global__ __launch_bounds__(256, 1) void gru_persist(
    const _Float16* __restrict__ x16,
    const _Float16* __restrict__ w0p, const _Float16* __restrict__ w1p,
    const float* __restrict__ bx0, const float* __restrict__ bh0,
    const float* __restrict__ bx1, const float* __restrict__ bh1,
    const float* __restrict__ h0in,
    _Float16* __restrict__ h0f, _Float16* __restrict__ h1f,
    float* __restrict__ out, unsigned* __restrict__ bar)
{
  const int tid = threadIdx.x;
  const int wid = tid >> 6, lane = tid & 63;
  const int wg = blockIdx.x;
  const int layer = wg >> 7;
  const int rb_ = wg & 127;
  const int c = rb_ >> 1;           // col-group 0..63
  const int brow = (rb_ & 1) * 32;  // batch half
  const int lcol = lane & 15;
  const int lk = (lane >> 4) * 8;

  const _Float16* wf = layer ? w1p : w0p;
  const float* bx = layer ? bx1 : bx0;
  const float* bhp = layer ? bh1 : bh0;
  _Float16* hbuf = layer ? h1f : h0f;

  const int col = c * 16 + lcol;
  const float rbv = bhp[col] + bx[col];
  const float zbv = bhp[HH + col] + bx[HH + col];
  const float nhb = bhp[2 * HH + col];
  const float nxb = bx[2 * HH + col];

  // ---- weights resident in VGPRs: wave wid covers kst = wid*16 .. wid*16+15 ----
  half8 wb[3][16];
#pragma unroll
  for (int g = 0; g < 3; ++g) {
    const long tile = (long)(g * 64 + c);
#pragma unroll
    for (int i = 0; i < 16; ++i)
      wb[g][i] = *(const half8*)(wf + (tile * 64 + (wid * 16 + i)) * 512 + lane * 8);
  }

  // f32 h master state (waves 0,1): rows er0..er0+3 at column col
  const int er0 = brow + wid * 16 + (lane >> 4) * 4;
  float hreg[4] = {0.f, 0.f, 0.f, 0.f};
  if (wid < 2) {
#pragma unroll
    for (int j = 0; j < 4; ++j)
      hreg[j] = h0in[layer * NBH + (er0 + j) * HH + col];
  }

  __shared__ f32x4 red[4][2][3][64];

  volatile unsigned* arr = bar + (wg & 7) * 64;  // arrive counter line
  unsigned* rel = bar + 768;                      // release epoch line

  const int kb = (wid & 1) * 512;   // K-base within this wave's source
  for (int p = 0; p <= TT; ++p) {
    const bool act = layer ? (p >= 1) : (p < TT);
    if (act) {
      const int t = p - layer;
      const int rd = p & 1;
      const _Float16* hsrc = hbuf + rd * NBH;
      const _Float16* xsrc = layer ? (h0f + rd * NBH) : (x16 + (long)t * NBH);
      const _Float16* asrc = (wid < 2) ? hsrc : xsrc;

      half8 afr[2][16];
      if (layer == 0 && wid >= 2) {
        // x-half: read-only input, plain L2-cached vector loads
        const _Float16* abase = asrc + (long)(brow + lcol) * HH + kb + lk;
#pragma unroll
        for (int m = 0; m < 2; ++m)
#pragma unroll
          for (int ks = 0; ks < 16; ++ks)
            afr[m][ks] = *(const half8*)(abase + (long)m * 16 * HH + ks * 32);
      } else {
        // h data: L3-coherent bypass loads (written by other XCDs last phase)
        const u64_t* abase = (const u64_t*)(asrc + (long)(brow + lcol) * HH + kb + lk);
        u64_t av[2][16][2];
#pragma unroll
        for (int m = 0; m < 2; ++m)
#pragma unroll
          for (int ks = 0; ks < 16; ++ks) {
            const u64_t* q = abase + m * 4096 + ks * 8;
            av[m][ks][0] = __hip_atomic_load(q,     __ATOMIC_RELAXED, __HIP_MEMORY_SCOPE_AGENT);
            av[m][ks][1] = __hip_atomic_load(q + 1, __ATOMIC_RELAXED, __HIP_MEMORY_SCOPE_AGENT);
          }
#pragma unroll
        for (int m = 0; m < 2; ++m)
#pragma unroll
          for (int ks = 0; ks < 16; ++ks) {
            union { u64_t u[2]; half8 h; } cv;
            cv.u[0] = av[m][ks][0]; cv.u[1] = av[m][ks][1];
            afr[m][ks] = cv.h;
          }
      }

      f32x4 acc[2][3] = {};
#pragma unroll
      for (int m = 0; m < 2; ++m)
#pragma unroll
        for (int ks = 0; ks < 16; ++ks)
#pragma unroll
          for (int g = 0; g < 3; ++g)
            acc[m][g] = __builtin_amdgcn_mfma_f32_16x16x32_f16(afr[m][ks], wb[g][ks], acc[m][g], 0, 0, 0);

      // partial reduction across the 4 K-quarter waves
#pragma unroll
      for (int m = 0; m < 2; ++m)
#pragma unroll
        for (int g = 0; g < 3; ++g)
          red[wid][m][g][lane] = acc[m][g];
      __syncthreads();

      if (wid < 2) {
        const int m = wid;
        f32x4 rs = red[0][m][0][lane] + red[1][m][0][lane] + red[2][m][0][lane] + red[3][m][0][lane];
        f32x4 zs = red[0][m][1][lane] + red[1][m][1][lane] + red[2][m][1][lane] + red[3][m][1][lane];
        f32x4 nh = red[0][m][2][lane] + red[1][m][2][lane];
        f32x4 nx = red[2][m][2][lane] + red[3][m][2][lane];
        _Float16* hdst = hbuf + (rd ^ 1) * NBH;
        float* yo = out + (long)t * NBH;
#pragma unroll
        for (int j = 0; j < 4; ++j) {
          const int row = er0 + j;
          const float rg = 1.f / (1.f + __expf(-(rs[j] + rbv)));
          const float zg = 1.f / (1.f + __expf(-(zs[j] + zbv)));
          const float ng = tanhf(nx[j] + nxb + rg * (nh[j] + nhb));
          const float hn = (1.f - zg) * ng + zg * hreg[j];
          hreg[j] = hn;
          if (layer) yo[row * HH + col] = hn;
          _Float16 hf = (_Float16)hn;
          unsigned us = (unsigned)__builtin_bit_cast(unsigned short, hf);
          unsigned other = (unsigned)__shfl_xor((int)us, 1);
          if ((lane & 1) == 0) {
            unsigned packed = us | (other << 16);
            __hip_atomic_store((unsigned*)&hdst[row * HH + col], packed,
                               __ATOMIC_RELAXED, __HIP_MEMORY_SCOPE_AGENT);
          }
        }
      }
    }
    // ---- global barrier: tree arrive + master release ----
    asm volatile("s_waitcnt vmcnt(0)" ::: "memory");  // per-wave store drain
    __syncthreads();
    if (tid == 0) {
      const unsigned ep = (unsigned)(p + 1);
      __hip_atomic_fetch_add((unsigned*)arr, 1u, __ATOMIC_RELAXED, __HIP_MEMORY_SCOPE_AGENT);
      if (wg == 0) {
        const unsigned tgt = 32u * ep;   // 32 WGs per arrive line
        for (;;) {
          unsigned s0 = __hip_atomic_load(bar + 0 * 64, __ATOMIC_RELAXED, __HIP_MEMORY_SCOPE_AGENT);
          unsigned s1 = __hip_atomic_load(bar + 1 * 64, __ATOMIC_RELAXED, __HIP_MEMORY_SCOPE_AGENT);
          unsigned s2 = __hip_atomic_load(bar + 2 * 64, __ATOMIC_RELAXED, __HIP_MEMORY_SCOPE_AGENT);
          unsigned s3 = __hip_atomic_load(bar + 3 * 64, __ATOMIC_RELAXED, __HIP_MEMORY_SCOPE_AGENT);
          unsigned s4 = __hip_atomic_load(bar + 4 * 64, __ATOMIC_RELAXED, __HIP_MEMORY_SCOPE_AGENT);
          unsigned s5 = __hip_atomic_load(bar + 5 * 64, __ATOMIC_RELAXED, __HIP_MEMORY_SCOPE_AGENT);
          unsigned s6 = __hip_atomic_load(bar + 6 * 64, __ATOMIC_RELAXED, __HIP_MEMORY_SCOPE_AGENT);
          unsigned s7 = __hip_atomic_load(bar + 7 * 64, __ATOMIC_RELAXED, __HIP_MEMORY_SCOPE_AGENT);
          if (s0 >= tgt && s1 >= tgt && s2 >= tgt && s3 >= tgt &&
              s4 >= tgt && s5 >= tgt && s6 >= tgt && s7 >= tgt) break;
          __builtin_amdgcn_s_sleep(1);
        }
        __hip_atomic_store(rel, ep, __ATOMIC_RELAXED, __HIP_MEMORY_SCOPE_AGENT);
      } else {
        while (__hip_atomic_load(rel, __ATOMIC_RELAXED, __HIP_MEMORY_SCOPE_AGENT) < ep)
          __builtin_amdgcn_s_sleep(1);
      }
    }
    __syncthreads();
  }

  // final hidden states (f32 master)
  if (wid < 2) {
#pragma unroll
    for (int j = 0; j < 4; ++j)
      out[(long)TT * NBH + layer * NBH + (er0 + j) * HH + col] = hreg[j];
  }
}

// ---------------- launch ----------------
extern "C" void kernel_launch(void* const* d_in, const int* in_sizes, int n_in,
                              void* d_out, int out_size, void* d_ws, size_t ws_size,
                              hipStream_t stream) {
  const float* x   = (const float*)d_in[0];
  const float* h0  = (const float*)d_in[1];
  const float* Wx0 = (const float*)d_in[2];
  const float* bx0 = (const float*)d_in[3];
  const float* Wh0 = (const float*)d_in[4];
  const float* bh0 = (const float*)d_in[5];
  const float* Wx1 = (const float*)d_in[6];
  const float* bx1 = (const float*)d_in[7];
  const float* Wh1 = (const float*)d_in[8];
  const float* bh1 = (const float*)d_in[9];
  float* out = (float*)d_out;

  const long nTBH = (long)TT * BB * HH;
  const long nWP  = (long)192 * 64 * 64 * 8;

  char* p = (char*)d_ws;
  _Float16* x16 = (_Float16*)p;  p += nTBH * 2;     // 67.1 MB
  _Float16* w0p = (_Float16*)p;  p += nWP * 2;      // 12.6 MB
  _Float16* w1p = (_Float16*)p;  p += nWP * 2;      // 12.6 MB
  _Float16* h0f = (_Float16*)p;  p += 2 * (long)NBH * 2;
  _Float16* h1f = (_Float16*)p;  p += 2 * (long)NBH * 2;
  unsigned* bar = (unsigned*)p;  p += 4096;
  if ((size_t)(p - (char*)d_ws) > ws_size) {
    sentinel_kernel<<<1, 1, 0, stream>>>(out);
    return;
  }

  hipMemsetAsync(bar, 0, 4096, stream);
  cvt_f32_f16_kernel<<<2048, 256, 0, stream>>>(x, x16, nTBH);
  cvt_wpack_kernel<<<3072, 256, 0, stream>>>(Wh0, Wx0, w0p);
  cvt_wpack_kernel<<<3072, 256, 0, stream>>>(Wh1, Wx1, w1p);
  init_hf_kernel<<<512, 256, 0, stream>>>(h0, h0f, h1f);

  void* args[] = {(void*)&x16, (void*)&w0p, (void*)&w1p,
                  (void*)&bx0, (void*)&bh0, (void*)&bx1, (void*)&bh1,
                  (void*)&h0, (void*)&h0f, (void*)&h1f,
                  (void*)&out, (void*)&bar};
  hipError_t e = hipLaunchCooperativeKernel((const void*)gru_persist,
                                            dim3(NWG), dim3(256), args, 0, stream);
  if (e != hipSuccess) {
    gru_persist<<<NWG, 256, 0, stream>>>(x16, w0p, w1p, bx0, bh0, bx1, bh1,
                                         h0, h0f, h1f, out, bar);
  }
}